// Round 6
// baseline (328.012 us; speedup 1.0000x reference)
//
#include <hip/hip_runtime.h>
#include <math.h>

#define TWO_N 8192
#define NR 4096
#define D 256
#define BM 128
#define BN 128
#define BK 64
#define PMW (TWO_N / 64)  // u64 mask words per row

typedef __attribute__((ext_vector_type(8))) short bf16x8;
typedef __attribute__((ext_vector_type(4))) float f32x4;

#define AS1V const __attribute__((address_space(1))) void
#define AS3V __attribute__((address_space(3))) void

__device__ inline unsigned short f2bf(float x) {
  unsigned u = __builtin_bit_cast(unsigned, x);
  u += 0x7fffu + ((u >> 16) & 1u);  // RNE
  return (unsigned short)(u >> 16);
}

// One-time f32 -> bf16 conversion of all embeddings (8192x256) into ws.
__global__ void cvt_kernel(const float* __restrict__ emb, unsigned short* __restrict__ ebf) {
  const size_t i = ((size_t)blockIdx.x * 256 + threadIdx.x) * 8;
  const float4 a = *reinterpret_cast<const float4*>(emb + i);
  const float4 b = *reinterpret_cast<const float4*>(emb + i + 4);
  union { unsigned short s[8]; bf16x8 v; } o;
  o.s[0] = f2bf(a.x); o.s[1] = f2bf(a.y); o.s[2] = f2bf(a.z); o.s[3] = f2bf(a.w);
  o.s[4] = f2bf(b.x); o.s[5] = f2bf(b.y); o.s[6] = f2bf(b.z); o.s[7] = f2bf(b.w);
  *reinterpret_cast<bf16x8*>(ebf + i) = o.v;
}

// Pack neg_mask bytes (0/1) into bits: pm[row*128 + w] bit j = negm[row][w*64+j].
// 64 bytes -> one u64 per thread; coalesced uint4 reads.
__global__ void repack_kernel(const unsigned char* __restrict__ negm,
                              unsigned long long* __restrict__ pm) {
  const int t = blockIdx.x * 256 + threadIdx.x;  // word index
  const uint4* p = reinterpret_cast<const uint4*>(negm + (size_t)t * 64);
  unsigned long long w = 0;
#pragma unroll
  for (int q = 0; q < 4; ++q) {
    const uint4 v = p[q];
    unsigned b = 0;
    b |= (v.x & 1u) | ((v.x >> 7) & 2u) | ((v.x >> 14) & 4u) | ((v.x >> 21) & 8u);
    b |= ((v.y & 1u) | ((v.y >> 7) & 2u) | ((v.y >> 14) & 4u) | ((v.y >> 21) & 8u)) << 4;
    b |= ((v.z & 1u) | ((v.z >> 7) & 2u) | ((v.z >> 14) & 4u) | ((v.z >> 21) & 8u)) << 8;
    b |= ((v.w & 1u) | ((v.w >> 7) & 2u) | ((v.w >> 14) & 4u) | ((v.w >> 21) & 8u)) << 12;
    w |= (unsigned long long)b << (q * 16);
  }
  pm[t] = w;
}

// ap[i] = dot(emb[i], emb[i+NR]) (f32); also zero rowsum[i]. One wave/row.
__global__ void ap_zero_kernel(const float* __restrict__ emb, float* __restrict__ ap,
                               double* __restrict__ rowsum) {
  const int lane = threadIdx.x & 63;
  const int wid = threadIdx.x >> 6;
  const int i = blockIdx.x * 4 + wid;
  const float4 a = *reinterpret_cast<const float4*>(emb + (size_t)i * D + lane * 4);
  const float4 b = *reinterpret_cast<const float4*>(emb + (size_t)(i + NR) * D + lane * 4);
  float s = a.x * b.x + a.y * b.y + a.z * b.z + a.w * b.w;
#pragma unroll
  for (int off = 32; off >= 1; off >>= 1) s += __shfl_xor(s, off, 64);
  if (lane == 0) { ap[i] = s; rowsum[i] = 0.0; }
}

// Fused bf16-MFMA GEMM (S = E[0:4096] * E^T) + bitmasked sum of e^(s-ap) in f64.
// Double-buffered LDS, STAGE(next) issued before compute(cur) so the
// __syncthreads vmcnt-drain lands after MFMA (T3 minimum-2-phase).
__global__ __launch_bounds__(256, 2) void fused_mfma(
    const unsigned short* __restrict__ ebf, const unsigned long long* __restrict__ pm,
    const float* __restrict__ ap, double* __restrict__ rowsum) {
  __shared__ unsigned short As[2][BM * BK];
  __shared__ unsigned short Bs[2][BN * BK];
  const int t = threadIdx.x;
  const int lane = t & 63;
  const int wid = t >> 6;
  const int wr = wid >> 1;
  const int wc = wid & 1;
  // XCD-aware bijective swizzle: grid 2048 = 8 * 256.
  const int sw = (blockIdx.x & 7) * 256 + (blockIdx.x >> 3);
  const int bi = sw >> 6;  // 0..31 row tile
  const int bj = sw & 63;  // 0..63 col tile

  f32x4 acc[4][4] = {};

  const int srow = lane >> 3;       // 0..7
  const int scol = (lane & 7) * 8;  // bf16 col within BK

  auto STAGE = [&](int buf, int kt) {
    const int k0 = kt * BK;
#pragma unroll
    for (int q = 0; q < 4; ++q) {
      const int rbase = wid * 32 + q * 8;  // wave-uniform
      const unsigned short* gA = ebf + (size_t)(bi * BM + rbase + srow) * D + k0 + scol;
      const unsigned short* gB = ebf + (size_t)(bj * BN + rbase + srow) * D + k0 + scol;
      __builtin_amdgcn_global_load_lds((AS1V*)gA, (AS3V*)(As[buf] + rbase * BK), 16, 0, 0);
      __builtin_amdgcn_global_load_lds((AS1V*)gB, (AS3V*)(Bs[buf] + rbase * BK), 16, 0, 0);
    }
  };

  STAGE(0, 0);
  __syncthreads();  // drains vmcnt before barrier (compiler-emitted)
  int cur = 0;
  for (int kt = 0; kt < D / BK; ++kt) {
    if (kt < D / BK - 1) STAGE(cur ^ 1, kt + 1);  // prefetch next tile first
#pragma unroll
    for (int kk = 0; kk < 2; ++kk) {
      bf16x8 af[4], bfr[4];
      const int kof = kk * 32 + (lane >> 4) * 8;
#pragma unroll
      for (int m = 0; m < 4; ++m)
        af[m] = *reinterpret_cast<const bf16x8*>(&As[cur][(wr * 64 + m * 16 + (lane & 15)) * BK + kof]);
#pragma unroll
      for (int n = 0; n < 4; ++n)
        bfr[n] = *reinterpret_cast<const bf16x8*>(&Bs[cur][(wc * 64 + n * 16 + (lane & 15)) * BK + kof]);
#pragma unroll
      for (int m = 0; m < 4; ++m)
#pragma unroll
        for (int n = 0; n < 4; ++n)
          acc[m][n] = __builtin_amdgcn_mfma_f32_16x16x32_bf16(af[m], bfr[n], acc[m][n], 0, 0, 0);
    }
    __syncthreads();  // waits lgkm (our ds_reads) + vmcnt (prefetch) for all waves
    cur ^= 1;
  }

  // Epilogue. C/D layout: col = lane&15, row = (lane>>4)*4 + reg (m89-verified).
  // e^x = exp2f(frac) * 2^k in f64: exponent field stays in (0,2046) -> always finite.
  const int g = lane >> 4;
  const int cl = lane & 15;
  double rs[4][4] = {};

#pragma unroll
  for (int m = 0; m < 4; ++m) {
    const int rowbase = bi * BM + wr * 64 + m * 16 + g * 4;
#pragma unroll
    for (int r2 = 0; r2 < 4; ++r2) {
      const int row = rowbase + r2;
      const float apv = ap[row];
      const unsigned long long mw = pm[(size_t)row * PMW + bj * 2 + wc];  // broadcast
#pragma unroll
      for (int n = 0; n < 4; ++n) {
        const float x = acc[m][n][r2] - apv;
        const float tt = x * 1.44269504088896340736f;
        const float kf = floorf(tt);
        const float mant = exp2f(tt - kf);
        const long long ebits = (long long)(1023 + (int)kf) << 52;
        const double sc = __builtin_bit_cast(double, ebits);
        const bool msk = (mw >> (n * 16 + cl)) & 1;
        rs[m][r2] += msk ? (double)mant * sc : 0.0;
      }
    }
  }
#pragma unroll
  for (int m = 0; m < 4; ++m)
#pragma unroll
    for (int r2 = 0; r2 < 4; ++r2) {
      double v = rs[m][r2];
#pragma unroll
      for (int off = 8; off >= 1; off >>= 1) v += __shfl_xor(v, off, 64);
      if (cl == 0) atomicAdd(&rowsum[bi * BM + wr * 64 + m * 16 + g * 4 + r2], v);
    }
}

// j_i = log1p(rowsum_i) in f64 (finite); mean over rows.
__global__ void finalize_kernel(const double* __restrict__ rowsum, float* __restrict__ out) {
  __shared__ double red[4];
  const int t = threadIdx.x;
  double s = 0.0;
  for (int i = t; i < NR; i += 256) s += log1p(rowsum[i]);
#pragma unroll
  for (int off = 32; off >= 1; off >>= 1) s += __shfl_xor(s, off, 64);
  if ((t & 63) == 0) red[t >> 6] = s;
  __syncthreads();
  if (t == 0) out[0] = (float)((red[0] + red[1] + red[2] + red[3]) * (1.0 / NR));
}

extern "C" void kernel_launch(void* const* d_in, const int* in_sizes, int n_in,
                              void* d_out, int out_size, void* d_ws, size_t ws_size,
                              hipStream_t stream) {
  const float* emb = (const float*)d_in[0];
  // d_in[1] (pos_mask) unused by the reference.
  const unsigned char* negm = (const unsigned char*)d_in[2];
  float* out = (float*)d_out;
  char* ws = (char*)d_ws;
  unsigned short* ebf = (unsigned short*)ws;                        // 4 MB bf16 embeddings
  unsigned long long* pm = (unsigned long long*)(ws + (1u << 22));  // 4 MB packed mask
  float* ap = (float*)(ws + (2u << 22));                            // 16 KB
  double* rowsum = (double*)(ws + (2u << 22) + 16384);              // 32 KB

  cvt_kernel<<<dim3(TWO_N * D / 8 / 256), dim3(256), 0, stream>>>(emb, ebf);
  repack_kernel<<<dim3(NR * PMW / 256), dim3(256), 0, stream>>>(negm, pm);
  ap_zero_kernel<<<dim3(NR / 4), dim3(256), 0, stream>>>(emb, ap, rowsum);
  fused_mfma<<<dim3((NR / BM) * (TWO_N / BN)), dim3(256), 0, stream>>>(ebf, pm, ap, rowsum);
  finalize_kernel<<<dim3(1), dim3(256), 0, stream>>>(rowsum, out);
}